// Round 1
// baseline (1713.223 us; speedup 1.0000x reference)
//
#include <hip/hip_runtime.h>
#include <math.h>

// ---------------------------------------------------------------------------
// NatureCNN_10496900071444: conv×3 -> flatten | lin1+relu -> lin2 -> concat
// -> 2×(2-layer LSTM, H=100, state carry) -> fc1+relu -> fc2.  N=2048 samples.
// Round 1: correctness-first fp32. Convs as implicit-im2col tiled GEMMs.
// ---------------------------------------------------------------------------

__device__ __forceinline__ float sigmoidf_(float x){ return 1.0f/(1.0f+__expf(-x)); }
__device__ __forceinline__ float tanhf_(float x){
  float e = __expf(-2.0f*fabsf(x));
  float t = (1.0f - e)/(1.0f + e);
  return copysignf(t, x);
}

// Generic fp32 GEMM: C[M,N] = act(A * B^T + bias), B is [N,K] row-major (torch weight).
// AMODE 0: A[row*lda + k].  AMODE 1: implicit im2col gather from NCHW tensor.
// CMODE 0: C[row*ldc + col].  CMODE 1: C[n*cstride + col*HO*WO + p], row=(n,p).
template<int BM,int BN,int AMODE,int CMODE,int RELU,
         int CIN,int HI,int WI,int KH,int KW,int ST,int HO,int WO>
__global__ __launch_bounds__(256) void gemm_k(
    const float* __restrict__ A, const float* __restrict__ B,
    float* __restrict__ C, const float* __restrict__ bias,
    int M, int N, int K, int lda, int ldb, int ldc, int cstride)
{
  __shared__ float As[16][BM+4];   // +4 pad: 16B-aligned rows, conflict-free
  __shared__ float Bs[16][BN+4];
  constexpr int HOWO = HO*WO;
  constexpr int KHKW = KH*KW;
  const int tid = threadIdx.x;
  const int bm = blockIdx.x * BM, bn = blockIdx.y * BN;
  constexpr int TX = BN/4;          // threads along N; TX*(BM/4)==256
  const int tx = tid % TX, ty = tid / TX;
  float acc[4][4] = {{0.f}};

  for (int kt = 0; kt < K; kt += 16){
    #pragma unroll
    for (int i = 0; i < (BM*16)/256; ++i){
      int e = tid + i*256;
      int m = e >> 4, kk = e & 15;
      int row = bm + m, k = kt + kk;
      float v = 0.f;
      if (row < M && k < K){
        if (AMODE == 0){
          v = A[(size_t)row*lda + k];
        } else {
          int n = row / HOWO, p = row - n*HOWO;
          int oy = p / WO,    ox = p - oy*WO;
          int ic = k / KHKW,  r  = k - ic*KHKW;
          int ky = r / KW,    kx = r - ky*KW;
          v = A[(((size_t)n*CIN + ic)*HI + oy*ST + ky)*WI + ox*ST + kx];
        }
      }
      As[kk][m] = v;
    }
    #pragma unroll
    for (int i = 0; i < (BN*16)/256; ++i){
      int e = tid + i*256;
      int nn = e >> 4, kk = e & 15;
      int col = bn + nn, k = kt + kk;
      float v = 0.f;
      if (col < N && k < K) v = B[(size_t)col*ldb + k];
      Bs[kk][nn] = v;
    }
    __syncthreads();
    #pragma unroll
    for (int kk = 0; kk < 16; ++kk){
      float a[4], b[4];
      #pragma unroll
      for (int i=0;i<4;i++) a[i] = As[kk][ty*4+i];
      #pragma unroll
      for (int j=0;j<4;j++) b[j] = Bs[kk][tx*4+j];
      #pragma unroll
      for (int i=0;i<4;i++)
        #pragma unroll
        for (int j=0;j<4;j++) acc[i][j] += a[i]*b[j];
    }
    __syncthreads();
  }

  #pragma unroll
  for (int i=0;i<4;i++){
    int row = bm + ty*4 + i;
    if (row >= M) continue;
    #pragma unroll
    for (int j=0;j<4;j++){
      int col = bn + tx*4 + j;
      if (col >= N) continue;
      float v = acc[i][j];
      if (bias) v += bias[col];
      if (RELU) v = fmaxf(v, 0.f);
      if (CMODE == 0){
        C[(size_t)row*ldc + col] = v;
      } else {
        int n = row / HOWO, p = row - n*HOWO;
        C[(size_t)n*cstride + col*HOWO + p] = v;
      }
    }
  }
}

// Transpose six [400,100] recurrent weight matrices to [100,400] for coalesced
// per-gate register loads in the LSTM kernel.
__global__ void transpose6_k(const float* s0,const float* s1,const float* s2,
                             const float* s3,const float* s4,const float* s5,
                             float* __restrict__ dst)
{
  const float* srcs[6] = {s0,s1,s2,s3,s4,s5};
  int w = blockIdx.y;
  const float* src = srcs[w];
  float* d = dst + (size_t)w*40000;
  int e = blockIdx.x*blockDim.x + threadIdx.x;
  if (e < 40000){
    int k = e/400, g = e - k*400;   // dst[k*400+g] = src[g*100+k]
    d[e] = src[g*100 + k];
  }
}

// One block per segment (b = 0..31). Each block runs: stack-S (zero init) then
// stack-R (init = stack-S final states), each 2 layers x 32 steps. Gate g is
// owned by thread g (<400); recurrent/input weight rows live in registers.
__global__ __launch_bounds__(512,2) void lstm_k(
    const float* __restrict__ X0s, const float* __restrict__ X0r,
    const float* __restrict__ wT,   // 6 x [100,400]: s_whh0,s_wih1,s_whh1,r_whh0,r_wih1,r_whh1
    const float* __restrict__ s_bih0, const float* __restrict__ s_bhh0,
    const float* __restrict__ s_bih1, const float* __restrict__ s_bhh1,
    const float* __restrict__ r_bih0, const float* __restrict__ r_bhh0,
    const float* __restrict__ r_bih1, const float* __restrict__ r_bhh1,
    float* __restrict__ outS, float* __restrict__ outR)
{
  __shared__ alignas(16) float h0[100];
  __shared__ alignas(16) float c0[100];
  __shared__ alignas(16) float h1[100];
  __shared__ alignas(16) float c1[100];
  __shared__ float gates[400];
  __shared__ alignas(16) float hbuf[3200];   // layer-0 outputs, 32 steps x 100

  const int b = blockIdx.x, tid = threadIdx.x;
  const int g = tid;
  if (tid < 100){ h0[tid]=0.f; c0[tid]=0.f; h1[tid]=0.f; c1[tid]=0.f; }
  __syncthreads();

  #pragma unroll 1
  for (int s = 0; s < 2; ++s){
    const float* Xp   = (s ? X0r : X0s) + (size_t)b*32*400;
    const float* w0T  = wT + (size_t)(s ? 3 : 0)*40000;
    const float* w1xT = wT + (size_t)(s ? 4 : 1)*40000;
    const float* w1hT = wT + (size_t)(s ? 5 : 2)*40000;
    const float* bi0 = s ? r_bih0 : s_bih0;
    const float* bh0 = s ? r_bhh0 : s_bhh0;
    const float* bi1 = s ? r_bih1 : s_bih1;
    const float* bh1 = s ? r_bhh1 : s_bhh1;

    // ------------- layer 0 -------------
    {
      float wr[100];
      float bsum = 0.f;
      if (g < 400){
        #pragma unroll
        for (int k=0;k<100;k++) wr[k] = w0T[k*400+g];
        bsum = bi0[g] + bh0[g];
      }
      #pragma unroll 1
      for (int t=0;t<32;t++){
        if (g < 400){
          const float4* h4 = (const float4*)h0;
          float a0=0.f,a1=0.f,a2=0.f,a3=0.f;
          #pragma unroll
          for (int kq=0;kq<25;kq++){
            float4 hv = h4[kq];
            a0 += hv.x*wr[4*kq+0];
            a1 += hv.y*wr[4*kq+1];
            a2 += hv.z*wr[4*kq+2];
            a3 += hv.w*wr[4*kq+3];
          }
          gates[g] = Xp[t*400+g] + bsum + ((a0+a1)+(a2+a3));
        }
        __syncthreads();
        if (tid < 100){
          float i_s = sigmoidf_(gates[tid]);
          float f_s = sigmoidf_(gates[100+tid]);
          float g_t = tanhf_(gates[200+tid]);
          float o_s = sigmoidf_(gates[300+tid]);
          float cn = f_s*c0[tid] + i_s*g_t;
          c0[tid] = cn;
          float hn = o_s*tanhf_(cn);
          h0[tid] = hn;
          hbuf[t*100+tid] = hn;
        }
        __syncthreads();
      }
    }
    // ------------- layer 1 -------------
    {
      float wx[100], wh[100];
      float bsum = 0.f;
      if (g < 400){
        #pragma unroll
        for (int k=0;k<100;k++){ wx[k] = w1xT[k*400+g]; wh[k] = w1hT[k*400+g]; }
        bsum = bi1[g] + bh1[g];
      }
      #pragma unroll 1
      for (int t=0;t<32;t++){
        if (g < 400){
          const float4* x4 = (const float4*)&hbuf[t*100];
          const float4* h4 = (const float4*)h1;
          float a0=0.f,a1=0.f,a2=0.f,a3=0.f;
          #pragma unroll
          for (int kq=0;kq<25;kq++){
            float4 xv = x4[kq]; float4 hv = h4[kq];
            a0 += xv.x*wx[4*kq+0] + hv.x*wh[4*kq+0];
            a1 += xv.y*wx[4*kq+1] + hv.y*wh[4*kq+1];
            a2 += xv.z*wx[4*kq+2] + hv.z*wh[4*kq+2];
            a3 += xv.w*wx[4*kq+3] + hv.w*wh[4*kq+3];
          }
          gates[g] = bsum + ((a0+a1)+(a2+a3));
        }
        __syncthreads();
        if (tid < 100){
          float i_s = sigmoidf_(gates[tid]);
          float f_s = sigmoidf_(gates[100+tid]);
          float g_t = tanhf_(gates[200+tid]);
          float o_s = sigmoidf_(gates[300+tid]);
          float cn = f_s*c1[tid] + i_s*g_t;
          c1[tid] = cn;
          float hn = o_s*tanhf_(cn);
          h1[tid] = hn;
          if (t == 31){
            float* dst = s ? outR : outS;
            dst[b*100+tid] = hn;
          }
        }
        __syncthreads();
      }
    }
    // stack 2 inits from the live (h0,c0,h1,c1) — exactly the reference carry.
  }
}

// Final head: out = relu([outR|outS] @ fc1^T + b1) @ fc2^T + b2, one block per row.
__global__ __launch_bounds__(256) void head_k(
    const float* __restrict__ outR, const float* __restrict__ outS,
    const float* __restrict__ f1w, const float* __restrict__ f1b,
    const float* __restrict__ f2w, const float* __restrict__ f2b,
    float* __restrict__ out)
{
  __shared__ float xin[200];
  __shared__ float mid[512];
  int b = blockIdx.x, tid = threadIdx.x;
  if (tid < 100) xin[tid] = outR[b*100+tid];
  else if (tid < 200) xin[tid] = outS[b*100+tid-100];
  __syncthreads();
  for (int j = tid; j < 512; j += 256){
    float acc = f1b[j];
    #pragma unroll 4
    for (int k=0;k<200;k++) acc += xin[k]*f1w[j*200+k];
    mid[j] = fmaxf(acc, 0.f);
  }
  __syncthreads();
  if (tid < 130){
    float acc = f2b[tid];
    #pragma unroll 4
    for (int k=0;k<512;k++) acc += mid[k]*f2w[tid*512+k];
    out[b*130+tid] = acc;
  }
}

extern "C" void kernel_launch(void* const* d_in, const int* in_sizes, int n_in,
                              void* d_out, int out_size, void* d_ws, size_t ws_size,
                              hipStream_t stream)
{
  const float* obs  = (const float*)d_in[0];
  const float* data = (const float*)d_in[1];
  const float* c1w = (const float*)d_in[2];  const float* c1b = (const float*)d_in[3];
  const float* c2w = (const float*)d_in[4];  const float* c2b = (const float*)d_in[5];
  const float* c3w = (const float*)d_in[6];  const float* c3b = (const float*)d_in[7];
  const float* l1w = (const float*)d_in[8];  const float* l1b = (const float*)d_in[9];
  const float* l2w = (const float*)d_in[10]; const float* l2b = (const float*)d_in[11];
  const float* s_wih0=(const float*)d_in[12]; const float* s_whh0=(const float*)d_in[13];
  const float* s_bih0=(const float*)d_in[14]; const float* s_bhh0=(const float*)d_in[15];
  const float* s_wih1=(const float*)d_in[16]; const float* s_whh1=(const float*)d_in[17];
  const float* s_bih1=(const float*)d_in[18]; const float* s_bhh1=(const float*)d_in[19];
  const float* r_wih0=(const float*)d_in[20]; const float* r_whh0=(const float*)d_in[21];
  const float* r_bih0=(const float*)d_in[22]; const float* r_bhh0=(const float*)d_in[23];
  const float* r_wih1=(const float*)d_in[24]; const float* r_whh1=(const float*)d_in[25];
  const float* r_bih1=(const float*)d_in[26]; const float* r_bhh1=(const float*)d_in[27];
  const float* f1w=(const float*)d_in[28]; const float* f1b=(const float*)d_in[29];
  const float* f2w=(const float*)d_in[30]; const float* f2b=(const float*)d_in[31];
  float* out = (float*)d_out;
  float* ws  = (float*)d_ws;

  // workspace layout (floats); total ≈ 23.7M floats ≈ 95 MB
  size_t o = 0;
  float* out1 = ws + o; o += (size_t)2048*7200;   // conv1 out [n][32][15][15]
  float* out2 = ws + o; o += (size_t)2048*2304;   // conv2 out [n][64][6][6]
  float* feat = ws + o; o += (size_t)2048*1536;   // [n][1024 conv | 512 lin]
  float* X0s  = ws + o; o += (size_t)1024*400;    // stack-S layer0 gate pre-acts
  float* X0r  = ws + o; o += (size_t)1024*400;    // stack-R layer0 gate pre-acts
  float* wT   = ws + o; o += (size_t)6*40000;     // transposed recurrent weights
  float* outS = ws + o; o += 3200;                // stack-S last-step h1 [32][100]
  float* outR = ws + o; o += 3200;                // stack-R last-step h1 [32][100]
  float* lin1out = out1;  // reuse conv1 buffer: lin1 runs after conv2 consumed it
  (void)ws_size; (void)in_sizes; (void)n_in; (void)out_size;

  // conv1: implicit GEMM  M=2048*225 N=32 K=192  (obs read ~once)
  gemm_k<128,32,1,1,1, 3,64,64,8,8,4,15,15><<<dim3(3600,1),256,0,stream>>>(
      obs, c1w, out1, c1b, 460800, 32, 192, 0, 192, 0, 7200);
  // conv2: M=2048*36 N=64 K=512
  gemm_k<64,64,1,1,1, 32,15,15,4,4,2,6,6><<<dim3(1152,1),256,0,stream>>>(
      out1, c2w, out2, c2b, 73728, 64, 512, 0, 512, 0, 2304);
  // lin1 (+relu): M=2048 N=1024 K=1500 — writes into the (now free) out1 region
  gemm_k<64,64,0,0,1, 1,1,1,1,1,1,1,1><<<dim3(32,16),256,0,stream>>>(
      data, l1w, lin1out, l1b, 2048, 1024, 1500, 1500, 1500, 1024, 0);
  // conv3: M=2048*16 N=64 K=576 -> feat cols [0,1024) with row stride 1536
  gemm_k<64,64,1,1,1, 64,6,6,3,3,1,4,4><<<dim3(512,1),256,0,stream>>>(
      out2, c3w, feat, c3b, 32768, 64, 576, 0, 576, 0, 1536);
  // lin2 (no relu): M=2048 N=512 K=1024 -> feat cols [1024,1536)
  gemm_k<64,64,0,0,0, 1,1,1,1,1,1,1,1><<<dim3(32,8),256,0,stream>>>(
      lin1out, l2w, feat + 1024, l2b, 2048, 512, 1024, 1024, 1024, 1536, 0);
  // LSTM layer-0 input pre-activations (no bias; added in lstm_k)
  gemm_k<64,64,0,0,0, 1,1,1,1,1,1,1,1><<<dim3(16,7),256,0,stream>>>(
      feat, s_wih0, X0s, (const float*)nullptr, 1024, 400, 1536, 1536, 1536, 400, 0);
  gemm_k<64,64,0,0,0, 1,1,1,1,1,1,1,1><<<dim3(16,7),256,0,stream>>>(
      feat + (size_t)1024*1536, r_wih0, X0r, (const float*)nullptr,
      1024, 400, 1536, 1536, 1536, 400, 0);
  // transpose recurrent matrices for coalesced register caching
  transpose6_k<<<dim3(157,6),256,0,stream>>>(s_whh0, s_wih1, s_whh1,
                                             r_whh0, r_wih1, r_whh1, wT);
  // sequential LSTM: 32 independent segment-blocks, both stacks each
  lstm_k<<<32,512,0,stream>>>(X0s, X0r, wT,
                              s_bih0,s_bhh0,s_bih1,s_bhh1,
                              r_bih0,r_bhh0,r_bih1,r_bhh1, outS, outR);
  // head
  head_k<<<32,256,0,stream>>>(outR, outS, f1w, f1b, f2w, f2b, out);
}

// Round 2
// 471.097 us; speedup vs baseline: 3.6367x; 3.6367x over previous
//
#include <hip/hip_runtime.h>
#include <math.h>

// ---------------------------------------------------------------------------
// NatureCNN: conv×3 (implicit-im2col bf16 MFMA GEMMs, NHWC intermediates)
// | lin1+relu -> lin2 (bf16 MFMA) -> concat feat -> wih0 pre-act GEMMs (fp32 out)
// -> 2×(2-layer LSTM, fp32, spill-free) -> head.
// ---------------------------------------------------------------------------

typedef __attribute__((ext_vector_type(4))) float f32x4;
typedef __attribute__((ext_vector_type(8))) short s16x8;
typedef __attribute__((ext_vector_type(8))) unsigned short u16x8;

__device__ __forceinline__ unsigned short f2bf(float f){
  union { float f; unsigned int u; } v; v.f = f;
  unsigned int r = (v.u + 0x7fffu + ((v.u >> 16) & 1u)) >> 16;
  return (unsigned short)r;
}
__device__ __forceinline__ float sigmoidf_(float x){ return 1.0f/(1.0f+__expf(-x)); }
__device__ __forceinline__ float tanhf_(float x){
  float e = __expf(-2.0f*fabsf(x));
  float t = (1.0f - e)/(1.0f + e);
  return copysignf(t, x);
}

// ---------------------------------------------------------------------------
// prep kernels (tiny, memory-bound)
// ---------------------------------------------------------------------------
__global__ void cast_pad_k(const float* __restrict__ src, unsigned short* __restrict__ dst,
                           int rows, int ks, int kd){
  int total = rows*kd;
  for (int e = blockIdx.x*blockDim.x + threadIdx.x; e < total; e += gridDim.x*blockDim.x){
    int r = e / kd, k = e - r*kd;
    dst[e] = (k < ks) ? f2bf(src[(size_t)r*ks + k]) : (unsigned short)0;
  }
}
// OIHW -> O,(tap,ci) : dst[oc*K + tap*cin + ic] = src[oc*K + ic*khkw + tap]
__global__ void reorder_w_k(const float* __restrict__ src, unsigned short* __restrict__ dst,
                            int ocn, int cin, int khkw){
  int K = cin*khkw, total = ocn*K;
  for (int e = blockIdx.x*blockDim.x + threadIdx.x; e < total; e += gridDim.x*blockDim.x){
    int oc = e / K, r = e - oc*K;
    int tap = r / cin, ic = r - tap*cin;
    dst[e] = f2bf(src[(size_t)oc*K + ic*khkw + tap]);
  }
}
// wih0 [400][1536]: permute k<1024 from (oc*16+p) order to NHWC-flat (p*64+oc)
__global__ void permute_wih_k(const float* __restrict__ src, unsigned short* __restrict__ dst){
  int total = 400*1536;
  for (int e = blockIdx.x*blockDim.x + threadIdx.x; e < total; e += gridDim.x*blockDim.x){
    int g = e / 1536, k = e - g*1536;
    int ksrc = (k < 1024) ? ((k & 63)*16 + (k >> 6)) : k;
    dst[e] = f2bf(src[(size_t)g*1536 + ksrc]);
  }
}
// six [400][100] -> [100][400] fp32 (LSTM register-cache layout)
__global__ void transpose6_k(const float* s0,const float* s1,const float* s2,
                             const float* s3,const float* s4,const float* s5,
                             float* __restrict__ dst){
  const float* srcs[6] = {s0,s1,s2,s3,s4,s5};
  const float* src = srcs[blockIdx.y];
  float* d = dst + (size_t)blockIdx.y*40000;
  int e = blockIdx.x*blockDim.x + threadIdx.x;
  if (e < 40000){ int k = e/400, g = e - k*400; d[e] = src[g*100 + k]; }
}

// ---------------------------------------------------------------------------
// bf16 MFMA GEMM: C = act(A * B^T + bias); B is [N][K] bf16 row-major.
// AMODE 0: A bf16 [M][lda].  1: conv1 gather from fp32 NCHW obs (k=ic*64+ky*8+kx).
//          2: NHWC bf16 conv gather (k=(ky*KW+kx)*CIN+ic).
// CMODE 0: bf16 row-major [M][ldc].  2: bf16 feat scatter (n*cstride + p*64 + col).
//          3: fp32 row-major (X0 path).
// All M are multiples of BM=128; K multiples of BK=64. NGUARD guards N (X0: N=400).
// ---------------------------------------------------------------------------
template<int BM,int BN,int WAVES_M,int WAVES_N,int AMODE,int CMODE,int RELU,int NGUARD,
         int CIN,int HI,int WI,int KH,int KW,int ST,int HO,int WO>
__global__ __launch_bounds__(256) void mgemm(
    const void* __restrict__ Av, const unsigned short* __restrict__ B,
    void* __restrict__ Cv, const float* __restrict__ bias,
    int M, int N, int K, int lda, int ldc, int cstride)
{
  constexpr int BK = 64;
  constexpr int WROWS = BM / WAVES_M;
  constexpr int WCOLS = BN / WAVES_N;
  constexpr int MF = WROWS / 16;
  constexpr int NF = WCOLS / 16;
  constexpr int HOWO = HO*WO;
  __shared__ unsigned short As[BM*BK];
  __shared__ unsigned short Bs[BN*BK];
  const int tid = threadIdx.x;
  const int bm = blockIdx.x * BM;
  const int bn = blockIdx.y * BN;
  const int lane = tid & 63, w = tid >> 6;
  const int wm = w / WAVES_N, wn = w % WAVES_N;
  const int m0 = wm * WROWS, n0 = wn * WCOLS;

  f32x4 acc[MF][NF] = {};

  const int ar = tid >> 1;           // A-stage row (BM=128 assumed)
  const int as0 = 4 * (tid & 1);     // A-stage slot base
  const int row_g = bm + ar;
  // im2col row decomposition (compile-time divisors)
  int a_n = 0, a_oy = 0, a_ox = 0;
  if (AMODE != 0){ a_n = row_g / HOWO; int p = row_g - a_n*HOWO; a_oy = p / WO; a_ox = p - a_oy*WO; }

  for (int kt = 0; kt < K; kt += BK){
    // ---- stage A ----
    #pragma unroll
    for (int si = 0; si < 4; ++si){
      int s = as0 + si;
      int k0 = kt + s*8;
      u16x8 val;
      if constexpr (AMODE == 0){
        val = *(const u16x8*)((const unsigned short*)Av + (size_t)row_g*lda + k0);
      } else if constexpr (AMODE == 1){
        int ic = k0 >> 6, r = k0 & 63, ky = r >> 3;   // kx0 == 0 (k0 % 8 == 0)
        const float* src = (const float*)Av +
            (((size_t)(a_n*CIN + ic)*HI + a_oy*ST + ky)*WI + a_ox*ST);
        f32x4 f0 = *(const f32x4*)src;
        f32x4 f1 = *(const f32x4*)(src + 4);
        val[0]=f2bf(f0[0]); val[1]=f2bf(f0[1]); val[2]=f2bf(f0[2]); val[3]=f2bf(f0[3]);
        val[4]=f2bf(f1[0]); val[5]=f2bf(f1[1]); val[6]=f2bf(f1[2]); val[7]=f2bf(f1[3]);
      } else {
        int tap = k0 / CIN, ic0 = k0 - tap*CIN;       // 8 | CIN, so 8-contig in ic
        int ky = tap / KW, kx = tap - ky*KW;
        const unsigned short* src = (const unsigned short*)Av +
            (((size_t)(a_n*HI + a_oy*ST + ky)*WI + a_ox*ST + kx)*CIN + ic0);
        val = *(const u16x8*)src;
      }
      int phys = s ^ ((ar >> 1) & 7);
      *(u16x8*)&As[ar*BK + phys*8] = val;
    }
    // ---- stage B ----
    if constexpr (BN == 64){
      int br = tid >> 2, bs0 = 2*(tid & 3);
      #pragma unroll
      for (int si = 0; si < 2; ++si){
        int s = bs0 + si, k0 = kt + s*8;
        int n_g = bn + br;
        u16x8 val = {};
        if (!NGUARD || n_g < N) val = *(const u16x8*)(B + (size_t)n_g*K + k0);
        int phys = s ^ ((br >> 1) & 7);
        *(u16x8*)&Bs[br*BK + phys*8] = val;
      }
    } else {  // BN == 32
      int br = tid >> 3, s = tid & 7, k0 = kt + s*8;
      int n_g = bn + br;
      u16x8 val = {};
      if (!NGUARD || n_g < N) val = *(const u16x8*)(B + (size_t)n_g*K + k0);
      int phys = s ^ ((br >> 1) & 7);
      *(u16x8*)&Bs[br*BK + phys*8] = val;
    }
    __syncthreads();
    // ---- compute: 2 MFMA k-steps per staged BK=64 ----
    #pragma unroll
    for (int ks = 0; ks < 2; ++ks){
      s16x8 a[MF], b[NF];
      #pragma unroll
      for (int i = 0; i < MF; ++i){
        int row = m0 + i*16 + (lane & 15);
        int phys = (ks*4 + (lane >> 4)) ^ ((row >> 1) & 7);
        a[i] = *(const s16x8*)&As[row*BK + phys*8];
      }
      #pragma unroll
      for (int j = 0; j < NF; ++j){
        int row = n0 + j*16 + (lane & 15);
        int phys = (ks*4 + (lane >> 4)) ^ ((row >> 1) & 7);
        b[j] = *(const s16x8*)&Bs[row*BK + phys*8];
      }
      #pragma unroll
      for (int i = 0; i < MF; ++i)
        #pragma unroll
        for (int j = 0; j < NF; ++j)
          acc[i][j] = __builtin_amdgcn_mfma_f32_16x16x32_bf16(a[i], b[j], acc[i][j], 0, 0, 0);
    }
    __syncthreads();
  }

  // ---- epilogue ----
  if constexpr (CMODE == 3){
    float* Cf = (float*)Cv;
    #pragma unroll
    for (int i = 0; i < MF; ++i)
      #pragma unroll
      for (int j = 0; j < NF; ++j){
        int col = bn + n0 + j*16 + (lane & 15);
        float bv = (bias && (!NGUARD || col < N)) ? bias[col] : 0.f;
        #pragma unroll
        for (int q = 0; q < 4; ++q){
          int row = bm + m0 + i*16 + (lane >> 4)*4 + q;
          float v = acc[i][j][q] + bv;
          if (RELU) v = fmaxf(v, 0.f);
          if (!NGUARD || col < N) Cf[(size_t)row*ldc + col] = v;
        }
      }
  } else {
    unsigned short* tile = As;   // reuse (BM*BN <= BM*BK)
    #pragma unroll
    for (int i = 0; i < MF; ++i)
      #pragma unroll
      for (int j = 0; j < NF; ++j){
        int col = n0 + j*16 + (lane & 15);
        float bv = bias ? bias[bn + col] : 0.f;
        #pragma unroll
        for (int q = 0; q < 4; ++q){
          int row = m0 + i*16 + (lane >> 4)*4 + q;
          float v = acc[i][j][q] + bv;
          if (RELU) v = fmaxf(v, 0.f);
          tile[row*BN + col] = f2bf(v);
        }
      }
    __syncthreads();
    unsigned short* Cu = (unsigned short*)Cv;
    constexpr int CHUNKS = (BM*BN)/(256*8);
    #pragma unroll
    for (int c = 0; c < CHUNKS; ++c){
      int flat = tid*8 + c*2048;
      int row = flat / BN, col = flat - (flat/BN)*BN;
      u16x8 v = *(const u16x8*)&tile[flat];
      int rg = bm + row;
      size_t addr;
      if constexpr (CMODE == 0) addr = (size_t)rg*ldc + bn + col;
      else { int n = rg >> 4, p = rg & 15; addr = (size_t)n*cstride + p*64 + col; }
      *(u16x8*)&Cu[addr] = v;
    }
  }
}

// ---------------------------------------------------------------------------
// LSTM: one block per segment; both stacks; spill-free phases (one 100-float
// weight array live at a time). Layer-1 x-part precomputed into LDS (no
// recurrence), recurrent loops carry only h·w_hh.
// ---------------------------------------------------------------------------
__global__ __launch_bounds__(512,1) void lstm_k(
    const float* __restrict__ X0s, const float* __restrict__ X0r,
    const float* __restrict__ wT,   // 6 x [100][400]: s_whh0,s_wih1,s_whh1,r_whh0,r_wih1,r_whh1
    const float* __restrict__ s_bih0, const float* __restrict__ s_bhh0,
    const float* __restrict__ s_bih1, const float* __restrict__ s_bhh1,
    const float* __restrict__ r_bih0, const float* __restrict__ r_bhh0,
    const float* __restrict__ r_bih1, const float* __restrict__ r_bhh1,
    float* __restrict__ outS, float* __restrict__ outR)
{
  __shared__ alignas(16) float h0[100];
  __shared__ alignas(16) float c0[100];
  __shared__ alignas(16) float h1[100];
  __shared__ alignas(16) float c1[100];
  __shared__ float gates[400];
  __shared__ alignas(16) float hbuf[3200];     // layer-0 outputs, 32 x 100
  __shared__ alignas(16) float Xl1[12800];     // layer-1 x-part pre-acts, 32 x 400

  const int b = blockIdx.x, tid = threadIdx.x;
  const int g = tid;
  if (tid < 100){ h0[tid]=0.f; c0[tid]=0.f; h1[tid]=0.f; c1[tid]=0.f; }
  __syncthreads();

  #pragma unroll 1
  for (int s = 0; s < 2; ++s){
    const float* Xp   = (s ? X0r : X0s) + (size_t)b*32*400;
    const float* w0T  = wT + (size_t)(s ? 3 : 0)*40000;
    const float* w1xT = wT + (size_t)(s ? 4 : 1)*40000;
    const float* w1hT = wT + (size_t)(s ? 5 : 2)*40000;
    const float* bi0 = s ? r_bih0 : s_bih0;
    const float* bh0 = s ? r_bhh0 : s_bhh0;
    const float* bi1 = s ? r_bih1 : s_bih1;
    const float* bh1 = s ? r_bhh1 : s_bhh1;

    // ------------- layer 0 (recurrent; wr in regs, X prefetched) -------------
    {
      float wr[100];
      float bsum = 0.f, xcur = 0.f;
      if (g < 400){
        #pragma unroll
        for (int k=0;k<100;k++) wr[k] = w0T[k*400+g];
        bsum = bi0[g] + bh0[g];
        xcur = Xp[g];
      }
      #pragma unroll 1
      for (int t=0;t<32;t++){
        float xnext = 0.f;
        if (g < 400 && t < 31) xnext = Xp[(t+1)*400+g];
        if (g < 400){
          const float4* h4 = (const float4*)h0;
          float a0=0.f,a1=0.f,a2=0.f,a3=0.f;
          #pragma unroll
          for (int kq=0;kq<25;kq++){
            float4 hv = h4[kq];
            a0 += hv.x*wr[4*kq+0];
            a1 += hv.y*wr[4*kq+1];
            a2 += hv.z*wr[4*kq+2];
            a3 += hv.w*wr[4*kq+3];
          }
          gates[g] = xcur + bsum + ((a0+a1)+(a2+a3));
        }
        __syncthreads();
        if (tid < 100){
          float i_s = sigmoidf_(gates[tid]);
          float f_s = sigmoidf_(gates[100+tid]);
          float g_t = tanhf_(gates[200+tid]);
          float o_s = sigmoidf_(gates[300+tid]);
          float cn = f_s*c0[tid] + i_s*g_t;
          c0[tid] = cn;
          float hn = o_s*tanhf_(cn);
          h0[tid] = hn;
          hbuf[t*100+tid] = hn;
        }
        __syncthreads();
        xcur = xnext;
      }
    }
    // ------------- layer 1a: x-part pre-acts (no recurrence) -------------
    {
      float wx[100];
      float bsum = 0.f;
      if (g < 400){
        #pragma unroll
        for (int k=0;k<100;k++) wx[k] = w1xT[k*400+g];
        bsum = bi1[g] + bh1[g];
        #pragma unroll 1
        for (int t=0;t<32;t++){
          const float4* x4 = (const float4*)&hbuf[t*100];
          float a0=0.f,a1=0.f,a2=0.f,a3=0.f;
          #pragma unroll
          for (int kq=0;kq<25;kq++){
            float4 xv = x4[kq];
            a0 += xv.x*wx[4*kq+0];
            a1 += xv.y*wx[4*kq+1];
            a2 += xv.z*wx[4*kq+2];
            a3 += xv.w*wx[4*kq+3];
          }
          Xl1[t*400+g] = bsum + ((a0+a1)+(a2+a3));
        }
      }
      __syncthreads();
    }
    // ------------- layer 1b: recurrent -------------
    {
      float wh[100];
      if (g < 400){
        #pragma unroll
        for (int k=0;k<100;k++) wh[k] = w1hT[k*400+g];
      }
      #pragma unroll 1
      for (int t=0;t<32;t++){
        if (g < 400){
          const float4* h4 = (const float4*)h1;
          float a0=0.f,a1=0.f,a2=0.f,a3=0.f;
          #pragma unroll
          for (int kq=0;kq<25;kq++){
            float4 hv = h4[kq];
            a0 += hv.x*wh[4*kq+0];
            a1 += hv.y*wh[4*kq+1];
            a2 += hv.z*wh[4*kq+2];
            a3 += hv.w*wh[4*kq+3];
          }
          gates[g] = Xl1[t*400+g] + ((a0+a1)+(a2+a3));
        }
        __syncthreads();
        if (tid < 100){
          float i_s = sigmoidf_(gates[tid]);
          float f_s = sigmoidf_(gates[100+tid]);
          float g_t = tanhf_(gates[200+tid]);
          float o_s = sigmoidf_(gates[300+tid]);
          float cn = f_s*c1[tid] + i_s*g_t;
          c1[tid] = cn;
          float hn = o_s*tanhf_(cn);
          h1[tid] = hn;
          if (t == 31){
            float* dst = s ? outR : outS;
            dst[b*100+tid] = hn;
          }
        }
        __syncthreads();
      }
    }
  }
}

// Final head: out = relu([outR|outS] @ fc1^T + b1) @ fc2^T + b2
__global__ __launch_bounds__(256) void head_k(
    const float* __restrict__ outR, const float* __restrict__ outS,
    const float* __restrict__ f1w, const float* __restrict__ f1b,
    const float* __restrict__ f2w, const float* __restrict__ f2b,
    float* __restrict__ out)
{
  __shared__ float xin[200];
  __shared__ float mid[512];
  int b = blockIdx.x, tid = threadIdx.x;
  if (tid < 100) xin[tid] = outR[b*100+tid];
  else if (tid < 200) xin[tid] = outS[b*100+tid-100];
  __syncthreads();
  for (int j = tid; j < 512; j += 256){
    float acc = f1b[j];
    #pragma unroll 4
    for (int k=0;k<200;k++) acc += xin[k]*f1w[j*200+k];
    mid[j] = fmaxf(acc, 0.f);
  }
  __syncthreads();
  if (tid < 130){
    float acc = f2b[tid];
    #pragma unroll 4
    for (int k=0;k<512;k++) acc += mid[k]*f2w[tid*512+k];
    out[b*130+tid] = acc;
  }
}

extern "C" void kernel_launch(void* const* d_in, const int* in_sizes, int n_in,
                              void* d_out, int out_size, void* d_ws, size_t ws_size,
                              hipStream_t stream)
{
  const float* obs  = (const float*)d_in[0];
  const float* data = (const float*)d_in[1];
  const float* c1w = (const float*)d_in[2];  const float* c1b = (const float*)d_in[3];
  const float* c2w = (const float*)d_in[4];  const float* c2b = (const float*)d_in[5];
  const float* c3w = (const float*)d_in[6];  const float* c3b = (const float*)d_in[7];
  const float* l1w = (const float*)d_in[8];  const float* l1b = (const float*)d_in[9];
  const float* l2w = (const float*)d_in[10]; const float* l2b = (const float*)d_in[11];
  const float* s_wih0=(const float*)d_in[12]; const float* s_whh0=(const float*)d_in[13];
  const float* s_bih0=(const float*)d_in[14]; const float* s_bhh0=(const float*)d_in[15];
  const float* s_wih1=(const float*)d_in[16]; const float* s_whh1=(const float*)d_in[17];
  const float* s_bih1=(const float*)d_in[18]; const float* s_bhh1=(const float*)d_in[19];
  const float* r_wih0=(const float*)d_in[20]; const float* r_whh0=(const float*)d_in[21];
  const float* r_bih0=(const float*)d_in[22]; const float* r_bhh0=(const float*)d_in[23];
  const float* r_wih1=(const float*)d_in[24]; const float* r_whh1=(const float*)d_in[25];
  const float* r_bih1=(const float*)d_in[26]; const float* r_bhh1=(const float*)d_in[27];
  const float* f1w=(const float*)d_in[28]; const float* f1b=(const float*)d_in[29];
  const float* f2w=(const float*)d_in[30]; const float* f2b=(const float*)d_in[31];
  float* out = (float*)d_out;
  (void)in_sizes; (void)n_in; (void)out_size;

  // ---- workspace layout (bytes, 256-aligned); total ≈ 67 MB ----
  char* p = (char*)d_ws;
  auto alloc = [&](size_t bytes){ void* r = (void*)p; p += (bytes + 255) & ~(size_t)255; return r; };
  unsigned short* data_bf = (unsigned short*)alloc((size_t)2048*1536*2);
  unsigned short* c1w_bf  = (unsigned short*)alloc((size_t)32*192*2);
  unsigned short* c2w_bf  = (unsigned short*)alloc((size_t)64*512*2);
  unsigned short* c3w_bf  = (unsigned short*)alloc((size_t)64*576*2);
  unsigned short* l1w_bf  = (unsigned short*)alloc((size_t)1024*1536*2);
  unsigned short* l2w_bf  = (unsigned short*)alloc((size_t)512*1024*2);
  unsigned short* wihS_bf = (unsigned short*)alloc((size_t)400*1536*2);
  unsigned short* wihR_bf = (unsigned short*)alloc((size_t)400*1536*2);
  unsigned short* conv1o  = (unsigned short*)alloc((size_t)2048*225*32*2);  // NHWC
  unsigned short* conv2o  = (unsigned short*)alloc((size_t)2048*36*64*2);   // NHWC
  unsigned short* feat    = (unsigned short*)alloc((size_t)2048*1536*2);
  unsigned short* lin1o   = (unsigned short*)alloc((size_t)2048*1024*2);
  float* X0s  = (float*)alloc((size_t)1024*400*4);
  float* X0r  = (float*)alloc((size_t)1024*400*4);
  float* wT   = (float*)alloc((size_t)6*40000*4);
  float* outS = (float*)alloc(3200*4);
  float* outR = (float*)alloc(3200*4);
  (void)ws_size;

  // ---- prep: casts / reorders (independent of GEMMs) ----
  cast_pad_k<<<1024,256,0,stream>>>(data, data_bf, 2048, 1500, 1536);
  cast_pad_k<<<512,256,0,stream>>>(l1w, l1w_bf, 1024, 1500, 1536);
  cast_pad_k<<<512,256,0,stream>>>(l2w, l2w_bf, 512, 1024, 1024);
  cast_pad_k<<<32,256,0,stream>>>(c1w, c1w_bf, 32, 192, 192);
  reorder_w_k<<<128,256,0,stream>>>(c2w, c2w_bf, 64, 32, 16);
  reorder_w_k<<<144,256,0,stream>>>(c3w, c3w_bf, 64, 64, 9);
  permute_wih_k<<<512,256,0,stream>>>(s_wih0, wihS_bf);
  permute_wih_k<<<512,256,0,stream>>>(r_wih0, wihR_bf);
  transpose6_k<<<dim3(157,6),256,0,stream>>>(s_whh0, s_wih1, s_whh1,
                                             r_whh0, r_wih1, r_whh1, wT);

  // ---- GEMM chain (bf16 MFMA, fp32 accumulate) ----
  // conv1: M=460800 N=32 K=192, obs fp32 NCHW gather -> NHWC bf16
  mgemm<128,32,4,1, 1,0,1,0, 3,64,64,8,8,4,15,15><<<dim3(3600,1),256,0,stream>>>(
      obs, c1w_bf, conv1o, c1b, 460800, 32, 192, 0, 32, 0);
  // conv2: M=73728 N=64 K=512, NHWC gather -> NHWC bf16
  mgemm<128,64,2,2, 2,0,1,0, 32,15,15,4,4,2,6,6><<<dim3(576,1),256,0,stream>>>(
      conv1o, c2w_bf, conv2o, c2b, 73728, 64, 512, 0, 64, 0);
  // lin1: M=2048 N=1024 K=1536(padded) -> bf16
  mgemm<128,64,2,2, 0,0,1,0, 1,1,1,1,1,1,1,1><<<dim3(16,16),256,0,stream>>>(
      data_bf, l1w_bf, lin1o, l1b, 2048, 1024, 1536, 1536, 1024, 0);
  // conv3: M=32768 N=64 K=576 -> feat cols [0,1024) in NHWC-flat order
  mgemm<128,64,2,2, 2,2,1,0, 64,6,6,3,3,1,4,4><<<dim3(256,1),256,0,stream>>>(
      conv2o, c3w_bf, feat, c3b, 32768, 64, 576, 0, 0, 1536);
  // lin2: M=2048 N=512 K=1024 -> feat cols [1024,1536)
  mgemm<128,64,2,2, 0,0,0,0, 1,1,1,1,1,1,1,1><<<dim3(16,8),256,0,stream>>>(
      lin1o, l2w_bf, feat + 1024, l2b, 2048, 512, 1024, 1024, 1536, 0);
  // LSTM layer-0 input pre-acts (fp32 out, no bias)
  mgemm<128,64,2,2, 0,3,0,1, 1,1,1,1,1,1,1,1><<<dim3(8,7),256,0,stream>>>(
      feat, wihS_bf, X0s, (const float*)nullptr, 1024, 400, 1536, 1536, 400, 0);
  mgemm<128,64,2,2, 0,3,0,1, 1,1,1,1,1,1,1,1><<<dim3(8,7),256,0,stream>>>(
      feat + (size_t)1024*1536, wihR_bf, X0r, (const float*)nullptr, 1024, 400, 1536, 1536, 400, 0);

  // ---- sequential LSTM (fp32) + head ----
  lstm_k<<<32,512,0,stream>>>(X0s, X0r, wT,
                              s_bih0,s_bhh0,s_bih1,s_bhh1,
                              r_bih0,r_bhh0,r_bih1,r_bhh1, outS, outR);
  head_k<<<32,256,0,stream>>>(outR, outS, f1w, f1b, f2w, f2b, out);
}